// Round 12
// baseline (591.781 us; speedup 1.0000x reference)
//
#include <hip/hip_runtime.h>

#define NN 50000
#define EE 800000

typedef unsigned short u16;
typedef unsigned int u32;
typedef __attribute__((ext_vector_type(8))) short short8;
typedef __attribute__((ext_vector_type(4))) float f32x4;
typedef __attribute__((ext_vector_type(2))) float f32x2;

__device__ __forceinline__ u16 f2bf(float f) {
    union { float f; u32 i; } v; v.f = f;
    u32 x = v.i;
    return (u16)((x + 0x7fffu + ((x >> 16) & 1u)) >> 16);  // RNE (prep only)
}
// pack two f32 -> bf16 pair (round-half-up): 2 add + 1 v_perm
__device__ __forceinline__ u32 pkr(float lo, float hi) {
    union { float f; u32 i; } a, b; a.f = lo; b.f = hi;
    return __builtin_amdgcn_perm(b.i + 0x8000u, a.i + 0x8000u, 0x07060302u);
}
// silu via hw rcp: avoids IEEE div sequence
__device__ __forceinline__ float siluf(float x) {
    return x * __builtin_amdgcn_rcpf(1.0f + __expf(-x));
}
__device__ __forceinline__ void atomic_pk_add_bf16(u16* addr, u32 data) {
    asm volatile("global_atomic_pk_add_bf16 %0, %1, off" :: "v"(addr), "v"(data) : "memory");
}

// B layout, column-interleaved tiles: group=n>>5, parity=n&1, slot=(n>>1)&15
__device__ __forceinline__ int b_idx2(int k, int n) {
    int chunk = ((k >> 5) << 3) + ((n >> 5) << 1) + (n & 1);
    return chunk * 512 + (((k >> 3) & 3) << 7) + (((n >> 1) & 15) << 3) + (k & 7);
}

// ---- h -> bf16 row-major ----
__global__ __launch_bounds__(256) void hconv_kernel(const float* __restrict__ h,
                                                    u16* __restrict__ hbf)
{
    int i = (blockIdx.x * 256 + threadIdx.x) * 8;
    float4 a = *(const float4*)(h + i);
    float4 b = *(const float4*)(h + i + 4);
    uint4 o = make_uint4(pkr(a.x, a.y), pkr(a.z, a.w), pkr(b.x, b.y), pkr(b.z, b.w));
    *(uint4*)(hbf + i) = o;
}

// ---- prep: fp32 weights -> bf16 interleaved fragment layout ----
__global__ __launch_bounds__(256) void prep_kernel(
    const float* __restrict__ We1, const float* __restrict__ We2,
    const float* __restrict__ Wc1, const float* __restrict__ Wn1,
    const float* __restrict__ Wn2, const float* __restrict__ Wv1,
    u16* __restrict__ We1bf, u16* __restrict__ We2bf, u16* __restrict__ Wc1bf,
    u16* __restrict__ Wn1bf, u16* __restrict__ Wn2bf, u16* __restrict__ Wv1bf)
{
    int i = blockIdx.x * 256 + threadIdx.x;     // 0..131071
    if (i < 32768) {
        int k = i >> 7, n = i & 127;
        We1bf[b_idx2(k, n)] = f2bf(We1[k * 128 + n]);   // rows 0..255
    } else if (i < 49152) {
        int t = i - 32768; int k = t >> 7, n = t & 127;
        We2bf[b_idx2(k, n)] = f2bf(We2[k * 128 + n]);
    } else if (i < 65536) {
        int t = i - 49152; int k = t >> 7, n = t & 127;
        Wc1bf[b_idx2(k, n)] = f2bf(Wc1[k * 128 + n]);
    } else if (i < 98304) {
        int t = i - 65536; int k = t >> 7, n = t & 127;
        Wn1bf[b_idx2(k, n)] = f2bf(Wn1[k * 128 + n]);   // rows 0..255
    } else if (i < 114688) {
        int t = i - 98304; int k = t >> 7, n = t & 127;
        Wn2bf[b_idx2(k, n)] = f2bf(Wn2[k * 128 + n]);
    } else {
        int t = i - 114688; int k = t >> 7, n = t & 127;
        Wv1bf[b_idx2(k, n)] = f2bf(Wv1[k * 128 + n]);
    }
}

// ---- edge kernel: BARRIER-FREE. 4 waves/block, each wave owns 32 edges ----
// Wave-private 8KB LDS scratch holds t1 then m (per-wave DS ordering => no barriers).
// Each wave computes all 128 cols (g = 0..3 col-groups).
__global__ __launch_bounds__(256, 4) void edge_kernel(
    const u16* __restrict__ hbf, const float* __restrict__ cdiff,
    const int* __restrict__ row, const int* __restrict__ col,
    const float* __restrict__ We1, const float* __restrict__ be1,
    const float* __restrict__ be2, const float* __restrict__ bc1,
    const float* __restrict__ Wc2,
    const u16* __restrict__ We1bf, const u16* __restrict__ We2bf,
    const u16* __restrict__ Wc1bf,
    u16* __restrict__ aggbf, float* __restrict__ fsum, float* __restrict__ cnt)
{
    __shared__ u16 scratch[4][4096];            // 8KB per wave

    const int tid = threadIdx.x;
    const int w = tid >> 6;
    const int lane = tid & 63;
    const int m15 = lane & 15, q = lane >> 4;
    const int e0 = blockIdx.x * 128 + w * 32;   // this wave's 32 edges
    u16* S = scratch[w];
    float* Sf = (float*)S;

    // swizzle constants (same verified machinery as R10/R11)
    const int lsw = (lane ^ q) * 8;
    const int a_ = m15 >> 2;
    const int sbase = (a_ << 7) + (q << 5) + ((m15 & 3) << 1);
    const int o0 = (0 ^ a_) << 3, o1 = (1 ^ a_) << 3, o2 = (2 ^ a_) << 3, o3 = (3 ^ a_) << 3;

    // radial + cnt (lanes 0..31 of this wave)
    if (lane < 32) {
        int e = e0 + lane;
        float cx = cdiff[(size_t)e * 3 + 0];
        float cy = cdiff[(size_t)e * 3 + 1];
        float cz = cdiff[(size_t)e * 3 + 2];
        Sf[lane] = cx * cx + cy * cy + cz * cz;
        atomicAdd(&cnt[row[e]], 1.0f);
    }

    // GEMM1 A bases: direct-from-global fragments (wave-unique, no redundancy)
    const u16* aR0 = hbf + (size_t)row[e0 + m15] * 128 + q * 8;
    const u16* aR1 = hbf + (size_t)row[e0 + 16 + m15] * 128 + q * 8;
    const u16* aC0 = hbf + (size_t)col[e0 + m15] * 128 + q * 8;
    const u16* aC1 = hbf + (size_t)col[e0 + 16 + m15] * 128 + q * 8;

    f32x4 acc[2][4][2];   // [mt][g][parity]

    // ---- GEMM1: t1 = silu(e_in @ We1 + be1), K=256 + radial rank-1 init ----
    {
        float rad[2][4];
        #pragma unroll
        for (int mt = 0; mt < 2; ++mt)
            #pragma unroll
            for (int r = 0; r < 4; ++r)
                rad[mt][r] = Sf[mt * 16 + q * 4 + r];      // wave-local LDS read
        #pragma unroll
        for (int g = 0; g < 4; ++g)
            #pragma unroll
            for (int p = 0; p < 2; ++p) {
                int n = g * 32 + 2 * m15 + p;
                float b = be1[n], wc = We1[256 * 128 + n];
                #pragma unroll
                for (int mt = 0; mt < 2; ++mt)
                    #pragma unroll
                    for (int r = 0; r < 4; ++r)
                        acc[mt][g][p][r] = fmaf(rad[mt][r], wc, b);
            }
    }
    #pragma unroll
    for (int c = 0; c < 8; ++c) {
        short8 a0 = *(const short8*)((c < 4 ? aR0 : aC0) + (c & 3) * 32);
        short8 a1 = *(const short8*)((c < 4 ? aR1 : aC1) + (c & 3) * 32);
        #pragma unroll
        for (int g = 0; g < 4; ++g)
            #pragma unroll
            for (int p = 0; p < 2; ++p) {
                short8 b = *(const short8*)(We1bf + (c * 8 + g * 2 + p) * 512 + lane * 8);
                acc[0][g][p] = __builtin_amdgcn_mfma_f32_16x16x32_bf16(a0, b, acc[0][g][p], 0, 0, 0);
                acc[1][g][p] = __builtin_amdgcn_mfma_f32_16x16x32_bf16(a1, b, acc[1][g][p], 0, 0, 0);
            }
    }
    // epilogue1: pack + store t1 to wave scratch (chunks (g*2+mt))
    #pragma unroll
    for (int mt = 0; mt < 2; ++mt)
        #pragma unroll
        for (int g = 0; g < 4; ++g) {
            u32 d0 = pkr(siluf(acc[mt][g][0][0]), siluf(acc[mt][g][1][0]));
            u32 d1 = pkr(siluf(acc[mt][g][0][1]), siluf(acc[mt][g][1][1]));
            u32 d2 = pkr(siluf(acc[mt][g][0][2]), siluf(acc[mt][g][1][2]));
            u32 d3 = pkr(siluf(acc[mt][g][0][3]), siluf(acc[mt][g][1][3]));
            u16* bp = S + (g * 2 + mt) * 512 + sbase;
            *(u32*)(bp + o0) = d0;
            *(u32*)(bp + o1) = d1;
            *(u32*)(bp + o2) = d2;
            *(u32*)(bp + o3) = d3;
        }

    // ---- GEMM2: m = silu(t1 @ We2 + be2), K=128 ----
    #pragma unroll
    for (int g = 0; g < 4; ++g)
        #pragma unroll
        for (int p = 0; p < 2; ++p) {
            float b = be2[g * 32 + 2 * m15 + p];
            #pragma unroll
            for (int mt = 0; mt < 2; ++mt)
                #pragma unroll
                for (int r = 0; r < 4; ++r)
                    acc[mt][g][p][r] = b;
        }
    #pragma unroll
    for (int c = 0; c < 4; ++c) {
        short8 a0 = *(const short8*)(S + (c * 2 + 0) * 512 + lsw);
        short8 a1 = *(const short8*)(S + (c * 2 + 1) * 512 + lsw);
        #pragma unroll
        for (int g = 0; g < 4; ++g)
            #pragma unroll
            for (int p = 0; p < 2; ++p) {
                short8 b = *(const short8*)(We2bf + (c * 8 + g * 2 + p) * 512 + lane * 8);
                acc[0][g][p] = __builtin_amdgcn_mfma_f32_16x16x32_bf16(a0, b, acc[0][g][p], 0, 0, 0);
                acc[1][g][p] = __builtin_amdgcn_mfma_f32_16x16x32_bf16(a1, b, acc[1][g][p], 0, 0, 0);
            }
    }
    // epilogue2: store m to scratch (same chunks; per-wave DS order makes WAR safe)
    // + packed agg atomics from registers
    {
        int rw[2][4];
        #pragma unroll
        for (int mt = 0; mt < 2; ++mt)
            #pragma unroll
            for (int r = 0; r < 4; ++r)
                rw[mt][r] = row[e0 + mt * 16 + q * 4 + r];
        #pragma unroll
        for (int mt = 0; mt < 2; ++mt)
            #pragma unroll
            for (int g = 0; g < 4; ++g) {
                u32 d4[4];
                #pragma unroll
                for (int r = 0; r < 4; ++r)
                    d4[r] = pkr(siluf(acc[mt][g][0][r]), siluf(acc[mt][g][1][r]));
                u16* bp = S + (g * 2 + mt) * 512 + sbase;
                *(u32*)(bp + o0) = d4[0];
                *(u32*)(bp + o1) = d4[1];
                *(u32*)(bp + o2) = d4[2];
                *(u32*)(bp + o3) = d4[3];
                #pragma unroll
                for (int r = 0; r < 4; ++r)
                    atomic_pk_add_bf16(aggbf + (size_t)rw[mt][r] * 128 + g * 32 + 2 * m15, d4[r]);
            }
    }

    // ---- GEMM3: u = silu(m @ Wc1 + bc1); coef fused ----
    #pragma unroll
    for (int g = 0; g < 4; ++g)
        #pragma unroll
        for (int p = 0; p < 2; ++p) {
            float b = bc1[g * 32 + 2 * m15 + p];
            #pragma unroll
            for (int mt = 0; mt < 2; ++mt)
                #pragma unroll
                for (int r = 0; r < 4; ++r)
                    acc[mt][g][p][r] = b;
        }
    #pragma unroll
    for (int c = 0; c < 4; ++c) {
        short8 a0 = *(const short8*)(S + (c * 2 + 0) * 512 + lsw);
        short8 a1 = *(const short8*)(S + (c * 2 + 1) * 512 + lsw);
        #pragma unroll
        for (int g = 0; g < 4; ++g)
            #pragma unroll
            for (int p = 0; p < 2; ++p) {
                short8 b = *(const short8*)(Wc1bf + (c * 8 + g * 2 + p) * 512 + lane * 8);
                acc[0][g][p] = __builtin_amdgcn_mfma_f32_16x16x32_bf16(a0, b, acc[0][g][p], 0, 0, 0);
                acc[1][g][p] = __builtin_amdgcn_mfma_f32_16x16x32_bf16(a1, b, acc[1][g][p], 0, 0, 0);
            }
    }
    // coef partials: pv[mt][r] = sum_{g,p} silu(u)*Wc2[col], then 16-lane reduce
    {
        float wc2[4][2];
        #pragma unroll
        for (int g = 0; g < 4; ++g)
            #pragma unroll
            for (int p = 0; p < 2; ++p)
                wc2[g][p] = Wc2[g * 32 + 2 * m15 + p];
        #pragma unroll
        for (int mt = 0; mt < 2; ++mt)
            #pragma unroll
            for (int r = 0; r < 4; ++r) {
                float pv = 0.f;
                #pragma unroll
                for (int g = 0; g < 4; ++g) {
                    pv = fmaf(siluf(acc[mt][g][0][r]), wc2[g][0], pv);
                    pv = fmaf(siluf(acc[mt][g][1][r]), wc2[g][1], pv);
                }
                pv += __shfl_xor(pv, 1);
                pv += __shfl_xor(pv, 2);
                pv += __shfl_xor(pv, 4);
                pv += __shfl_xor(pv, 8);
                if (m15 == 0) Sf[mt * 16 + q * 4 + r] = pv;   // coef -> wave scratch
            }
    }

    // force scatter (lanes 0..31, wave-local)
    if (lane < 32) {
        int e = e0 + lane;
        float coef = Sf[lane];
        int rr = row[e];
        #pragma unroll
        for (int ax = 0; ax < 3; ++ax) {
            float tr = cdiff[(size_t)e * 3 + ax] * coef;
            tr = fminf(fmaxf(tr, -100.f), 100.f);
            atomicAdd(&fsum[(size_t)rr * 3 + ax], tr);
        }
    }
}

// ---- node kernel: 64 nodes/block, 4 waves, ~34.5KB LDS (unchanged from R11) ----
__global__ __launch_bounds__(256, 4) void node_kernel(
    const u16* __restrict__ hbf,
    const float* __restrict__ bn1, const float* __restrict__ bn2,
    const float* __restrict__ bv1, const float* __restrict__ Wv2,
    const float* __restrict__ bv2,
    const u16* __restrict__ Wn1bf, const u16* __restrict__ Wn2bf,
    const u16* __restrict__ Wv1bf,
    const u16* __restrict__ aggbf, const float* __restrict__ fsum,
    const float* __restrict__ cnt, float* __restrict__ out)
{
    __shared__ u16 sX[16384];
    __shared__ float sBn1[128], sBn2[128], sBv1[128];
    __shared__ float sVelP[4][64];
    u16* sT = sX + 8192;

    const int tid = threadIdx.x;
    const int nblk = blockIdx.x * 64;
    const int w = tid >> 6;
    const int lane = tid & 63;
    const int m15 = lane & 15, q = lane >> 4;
    const int n0 = w * 32 + 2 * m15, n1 = n0 + 1;
    const int lsw = (lane ^ q) * 8;
    const int a_ = m15 >> 2;
    const int sbase = (a_ << 7) + (q << 5) + ((m15 & 3) << 1);
    const int o0 = (0 ^ a_) << 3, o1 = (1 ^ a_) << 3, o2 = (2 ^ a_) << 3, o3 = (3 ^ a_) << 3;
    const int ard = (m15 + 64 * q) * 8;

    if (tid < 192) {
        int r = tid / 3, ax = tid - r * 3;
        int n = nblk + r;
        if (n < NN)
            out[NN + (size_t)n * 3 + ax] = fsum[(size_t)n * 3 + ax] * __builtin_amdgcn_rcpf(fmaxf(cnt[n], 1.0f));
    }
    if (tid < 128) { sBn1[tid] = bn1[tid]; sBn2[tid] = bn2[tid]; sBv1[tid] = bv1[tid]; }
    const float wv2a = Wv2[n0], wv2b = Wv2[n1];

    {
        int r = tid & 63, j = tid >> 6;
        int n = nblk + r; if (n > NN - 1) n = NN - 1;
        const u16* src = ((j < 2) ? hbf : aggbf) + (size_t)n * 128 + (j & 1) * 64;
        #pragma unroll
        for (int i = 0; i < 8; ++i) {
            int slot = r + ((j * 8 + i) << 6);
            *(uint4*)&sX[slot * 8] = *(const uint4*)(src + i * 8);
        }
    }
    __syncthreads();

    f32x4 acc[4][2];

    {
        float b0 = sBn1[n0], b1 = sBn1[n1];
        #pragma unroll
        for (int mt = 0; mt < 4; ++mt)
            #pragma unroll
            for (int r = 0; r < 4; ++r) { acc[mt][0][r] = b0; acc[mt][1][r] = b1; }
    }
    #pragma unroll
    for (int c = 0; c < 8; ++c) {
        short8 bf0 = *(const short8*)(Wn1bf + (c * 8 + w * 2 + 0) * 512 + lane * 8);
        short8 bf1 = *(const short8*)(Wn1bf + (c * 8 + w * 2 + 1) * 512 + lane * 8);
        #pragma unroll
        for (int mt = 0; mt < 4; ++mt) {
            short8 af = *(const short8*)(sX + ard + c * 2048 + mt * 128);
            acc[mt][0] = __builtin_amdgcn_mfma_f32_16x16x32_bf16(af, bf0, acc[mt][0], 0, 0, 0);
            acc[mt][1] = __builtin_amdgcn_mfma_f32_16x16x32_bf16(af, bf1, acc[mt][1], 0, 0, 0);
        }
    }
    u32 dn[4][4];
    #pragma unroll
    for (int mt = 0; mt < 4; ++mt)
        #pragma unroll
        for (int r = 0; r < 4; ++r)
            dn[mt][r] = pkr(siluf(acc[mt][0][r]), siluf(acc[mt][1][r]));
    __syncthreads();
    #pragma unroll
    for (int mt = 0; mt < 4; ++mt) {
        u16* bp = sT + (w * 4 + mt) * 512 + sbase;
        *(u32*)(bp + o0) = dn[mt][0];
        *(u32*)(bp + o1) = dn[mt][1];
        *(u32*)(bp + o2) = dn[mt][2];
        *(u32*)(bp + o3) = dn[mt][3];
    }
    __syncthreads();

    {
        float b0 = sBn2[n0], b1 = sBn2[n1];
        #pragma unroll
        for (int mt = 0; mt < 4; ++mt)
            #pragma unroll
            for (int r = 0; r < 4; ++r) { acc[mt][0][r] = b0; acc[mt][1][r] = b1; }
    }
    #pragma unroll
    for (int c = 0; c < 4; ++c) {
        short8 bf0 = *(const short8*)(Wn2bf + (c * 8 + w * 2 + 0) * 512 + lane * 8);
        short8 bf1 = *(const short8*)(Wn2bf + (c * 8 + w * 2 + 1) * 512 + lane * 8);
        #pragma unroll
        for (int mt = 0; mt < 4; ++mt) {
            short8 af = *(const short8*)(sT + (c * 4 + mt) * 512 + lsw);
            acc[mt][0] = __builtin_amdgcn_mfma_f32_16x16x32_bf16(af, bf0, acc[mt][0], 0, 0, 0);
            acc[mt][1] = __builtin_amdgcn_mfma_f32_16x16x32_bf16(af, bf1, acc[mt][1], 0, 0, 0);
        }
    }
    #pragma unroll
    for (int mt = 0; mt < 4; ++mt)
        #pragma unroll
        for (int r = 0; r < 4; ++r) {
            int n = nblk + mt * 16 + q * 4 + r;
            if (n < NN) {
                f32x2 v; v.x = acc[mt][0][r]; v.y = acc[mt][1][r];
                *(f32x2*)(out + (size_t)4 * NN + (size_t)n * 128 + n0) = v;
            }
        }

    {
        float b0 = sBv1[n0], b1 = sBv1[n1];
        #pragma unroll
        for (int mt = 0; mt < 4; ++mt)
            #pragma unroll
            for (int r = 0; r < 4; ++r) { acc[mt][0][r] = b0; acc[mt][1][r] = b1; }
    }
    #pragma unroll
    for (int c = 0; c < 4; ++c) {
        short8 bf0 = *(const short8*)(Wv1bf + (c * 8 + w * 2 + 0) * 512 + lane * 8);
        short8 bf1 = *(const short8*)(Wv1bf + (c * 8 + w * 2 + 1) * 512 + lane * 8);
        #pragma unroll
        for (int mt = 0; mt < 4; ++mt) {
            short8 af = *(const short8*)(sX + ard + c * 2048 + mt * 128);
            acc[mt][0] = __builtin_amdgcn_mfma_f32_16x16x32_bf16(af, bf0, acc[mt][0], 0, 0, 0);
            acc[mt][1] = __builtin_amdgcn_mfma_f32_16x16x32_bf16(af, bf1, acc[mt][1], 0, 0, 0);
        }
    }
    #pragma unroll
    for (int mt = 0; mt < 4; ++mt)
        #pragma unroll
        for (int r = 0; r < 4; ++r) {
            float pv = fmaf(siluf(acc[mt][0][r]), wv2a, siluf(acc[mt][1][r]) * wv2b);
            pv += __shfl_xor(pv, 1);
            pv += __shfl_xor(pv, 2);
            pv += __shfl_xor(pv, 4);
            pv += __shfl_xor(pv, 8);
            if (m15 == 0) sVelP[w][mt * 16 + q * 4 + r] = pv;
        }
    __syncthreads();

    if (tid < 64) {
        int n = nblk + tid;
        if (n < NN)
            out[n] = bv2[0] + sVelP[0][tid] + sVelP[1][tid] + sVelP[2][tid] + sVelP[3][tid];
    }
}

extern "C" void kernel_launch(void* const* d_in, const int* in_sizes, int n_in,
                              void* d_out, int out_size, void* d_ws, size_t ws_size,
                              hipStream_t stream) {
    const float* h     = (const float*)d_in[0];
    const float* cdiff = (const float*)d_in[1];
    const int* row     = (const int*)d_in[2];
    const int* col     = (const int*)d_in[3];
    const float* We1 = (const float*)d_in[4];
    const float* be1 = (const float*)d_in[5];
    const float* We2 = (const float*)d_in[6];
    const float* be2 = (const float*)d_in[7];
    const float* Wn1 = (const float*)d_in[8];
    const float* bn1 = (const float*)d_in[9];
    const float* Wn2 = (const float*)d_in[10];
    const float* bn2 = (const float*)d_in[11];
    const float* Wc1 = (const float*)d_in[12];
    const float* bc1 = (const float*)d_in[13];
    const float* Wc2 = (const float*)d_in[14];
    const float* Wv1 = (const float*)d_in[15];
    const float* bv1 = (const float*)d_in[16];
    const float* Wv2 = (const float*)d_in[17];
    const float* bv2 = (const float*)d_in[18];

    u16* aggbf  = (u16*)d_ws;                           // [NN*128] bf16
    float* fsum = (float*)(aggbf + (size_t)NN * 128);   // [NN*3]
    float* cnt  = fsum + (size_t)NN * 3;                // [NN]
    u16* We1bf = (u16*)(cnt + NN);                      // [32768]
    u16* We2bf = We1bf + 32768;                         // [16384]
    u16* Wc1bf = We2bf + 16384;                         // [16384]
    u16* Wn1bf = Wc1bf + 16384;                         // [32768]
    u16* Wn2bf = Wn1bf + 32768;                         // [16384]
    u16* Wv1bf = Wn2bf + 16384;                         // [16384]
    u16* hbf   = Wv1bf + 16384;                         // [NN*128] bf16
    float* out = (float*)d_out;

    size_t zero_bytes = (size_t)NN * 128 * 2 + (size_t)NN * 3 * 4 + (size_t)NN * 4;
    hipMemsetAsync(d_ws, 0, zero_bytes, stream);

    hconv_kernel<<<3125, 256, 0, stream>>>(h, hbf);
    prep_kernel<<<512, 256, 0, stream>>>(We1, We2, Wc1, Wn1, Wn2, Wv1,
                                         We1bf, We2bf, Wc1bf, Wn1bf, Wn2bf, Wv1bf);
    edge_kernel<<<EE / 128, 256, 0, stream>>>(hbf, cdiff, row, col,
                                              We1, be1, be2, bc1, Wc2,
                                              We1bf, We2bf, Wc1bf,
                                              aggbf, fsum, cnt);
    node_kernel<<<(NN + 63) / 64, 256, 0, stream>>>(hbf, bn1, bn2, bv1, Wv2, bv2,
                                                    Wn1bf, Wn2bf, Wv1bf,
                                                    aggbf, fsum, cnt, out);
}

// Round 13
// 414.005 us; speedup vs baseline: 1.4294x; 1.4294x over previous
//
#include <hip/hip_runtime.h>

#define NN 50000
#define EE 800000

typedef unsigned short u16;
typedef unsigned int u32;
typedef __attribute__((ext_vector_type(8))) short short8;
typedef __attribute__((ext_vector_type(4))) float f32x4;
typedef __attribute__((ext_vector_type(2))) float f32x2;

__device__ __forceinline__ u16 f2bf(float f) {
    union { float f; u32 i; } v; v.f = f;
    u32 x = v.i;
    return (u16)((x + 0x7fffu + ((x >> 16) & 1u)) >> 16);  // RNE (prep only)
}
// pack two f32 -> bf16 pair (round-half-up): 2 add + 1 v_perm
__device__ __forceinline__ u32 pkr(float lo, float hi) {
    union { float f; u32 i; } a, b; a.f = lo; b.f = hi;
    return __builtin_amdgcn_perm(b.i + 0x8000u, a.i + 0x8000u, 0x07060302u);
}
// silu via hw rcp: avoids IEEE div sequence
__device__ __forceinline__ float siluf(float x) {
    return x * __builtin_amdgcn_rcpf(1.0f + __expf(-x));
}
__device__ __forceinline__ void atomic_pk_add_bf16(u16* addr, u32 data) {
    asm volatile("global_atomic_pk_add_bf16 %0, %1, off" :: "v"(addr), "v"(data) : "memory");
}

// B layout, column-interleaved tiles: group=n>>5, parity=n&1, slot=(n>>1)&15
__device__ __forceinline__ int b_idx2(int k, int n) {
    int chunk = ((k >> 5) << 3) + ((n >> 5) << 1) + (n & 1);
    return chunk * 512 + (((k >> 3) & 3) << 7) + (((n >> 1) & 15) << 3) + (k & 7);
}

// ---- h -> bf16 row-major ----
__global__ __launch_bounds__(256) void hconv_kernel(const float* __restrict__ h,
                                                    u16* __restrict__ hbf)
{
    int i = (blockIdx.x * 256 + threadIdx.x) * 8;
    float4 a = *(const float4*)(h + i);
    float4 b = *(const float4*)(h + i + 4);
    uint4 o = make_uint4(pkr(a.x, a.y), pkr(a.z, a.w), pkr(b.x, b.y), pkr(b.z, b.w));
    *(uint4*)(hbf + i) = o;
}

// ---- prep: fp32 weights -> bf16 interleaved fragment layout ----
__global__ __launch_bounds__(256) void prep_kernel(
    const float* __restrict__ We1, const float* __restrict__ We2,
    const float* __restrict__ Wc1, const float* __restrict__ Wn1,
    const float* __restrict__ Wn2, const float* __restrict__ Wv1,
    u16* __restrict__ We1bf, u16* __restrict__ We2bf, u16* __restrict__ Wc1bf,
    u16* __restrict__ Wn1bf, u16* __restrict__ Wn2bf, u16* __restrict__ Wv1bf)
{
    int i = blockIdx.x * 256 + threadIdx.x;     // 0..131071
    if (i < 32768) {
        int k = i >> 7, n = i & 127;
        We1bf[b_idx2(k, n)] = f2bf(We1[k * 128 + n]);   // rows 0..255
    } else if (i < 49152) {
        int t = i - 32768; int k = t >> 7, n = t & 127;
        We2bf[b_idx2(k, n)] = f2bf(We2[k * 128 + n]);
    } else if (i < 65536) {
        int t = i - 49152; int k = t >> 7, n = t & 127;
        Wc1bf[b_idx2(k, n)] = f2bf(Wc1[k * 128 + n]);
    } else if (i < 98304) {
        int t = i - 65536; int k = t >> 7, n = t & 127;
        Wn1bf[b_idx2(k, n)] = f2bf(Wn1[k * 128 + n]);   // rows 0..255
    } else if (i < 114688) {
        int t = i - 98304; int k = t >> 7, n = t & 127;
        Wn2bf[b_idx2(k, n)] = f2bf(Wn2[k * 128 + n]);
    } else {
        int t = i - 114688; int k = t >> 7, n = t & 127;
        Wv1bf[b_idx2(k, n)] = f2bf(Wv1[k * 128 + n]);
    }
}

// ---- edge kernel: 64 edges/block, 4 waves x (64 rows x 32 cols), ~34KB LDS ----
// Staging slot(e,kg) = e + 64*kg (line-tiled, conflict-free). B traffic halved
// vs 32-edge tile; barriers per edge halved. 4 blocks/CU.
__global__ __launch_bounds__(256, 4) void edge_kernel(
    const u16* __restrict__ hbf, const float* __restrict__ cdiff,
    const int* __restrict__ row, const int* __restrict__ col,
    const float* __restrict__ We1, const float* __restrict__ be1,
    const float* __restrict__ be2, const float* __restrict__ bc1,
    const float* __restrict__ Wc2,
    const u16* __restrict__ We1bf, const u16* __restrict__ We2bf,
    const u16* __restrict__ Wc1bf,
    u16* __restrict__ aggbf, float* __restrict__ fsum, float* __restrict__ cnt)
{
    __shared__ u16 sA[16384];      // 32KB e_in; after GEMM1: sT=sA[0:8K], sM=sA[8K:16K]
    __shared__ float sRad[64];
    __shared__ int sRow[64], sCol[64];
    __shared__ float sCoefP[4][64];
    u16* sT = sA;
    u16* sM = sA + 8192;

    const int tid = threadIdx.x;
    const int e0 = blockIdx.x * 64;
    const int w = tid >> 6;
    const int lane = tid & 63;
    const int m15 = lane & 15, q = lane >> 4;
    const int n0 = w * 32 + 2 * m15, n1 = n0 + 1;
    const int lsw = (lane ^ q) * 8;
    const int a_ = m15 >> 2;
    const int sbase = (a_ << 7) + (q << 5) + ((m15 & 3) << 1);
    const int o0 = (0 ^ a_) << 3, o1 = (1 ^ a_) << 3, o2 = (2 ^ a_) << 3, o3 = (3 ^ a_) << 3;
    const int ard = (m15 + 64 * q) * 8;        // GEMM1 A-read base (u16)

    // biases / scalars direct from L1 (no LDS staging barrier)
    const float b1a = be1[n0], b1b = be1[n1];
    const float w256a = We1[256 * 128 + n0], w256b = We1[256 * 128 + n1];
    const float b2a = be2[n0], b2b = be2[n1];
    const float b3a = bc1[n0], b3b = bc1[n1];
    const float wc2a = Wc2[n0], wc2b = Wc2[n1];

    if (tid < 64) {
        int e = e0 + tid;
        sRow[tid] = row[e]; sCol[tid] = col[e];
        float cx = cdiff[(size_t)e * 3 + 0];
        float cy = cdiff[(size_t)e * 3 + 1];
        float cz = cdiff[(size_t)e * 3 + 2];
        sRad[tid] = cx * cx + cy * cy + cz * cz;
        atomicAdd(&cnt[sRow[tid]], 1.0f);
    }

    // gather e_in: wave w loads quarter j=w; row/col direct from global (L1)
    {
        int e = tid & 63, j = tid >> 6;
        int node = (j < 2) ? row[e0 + e] : col[e0 + e];
        const u16* src = hbf + (size_t)node * 128 + (j & 1) * 64;
        #pragma unroll
        for (int i = 0; i < 8; ++i) {
            int slot = e + ((j * 8 + i) << 6);        // e + 64*kg
            *(uint4*)&sA[slot * 8] = *(const uint4*)(src + i * 8);
        }
    }
    __syncthreads();   // barrier 1: staging + gather complete

    f32x4 acc[4][2];
    u32 d[4][4];

    // ---- GEMM1: t1 = silu(e_in @ We1 + be1), K=256 + radial rank-1 init ----
    #pragma unroll
    for (int mt = 0; mt < 4; ++mt)
        #pragma unroll
        for (int r = 0; r < 4; ++r) {
            float rad = sRad[mt * 16 + q * 4 + r];
            acc[mt][0][r] = fmaf(rad, w256a, b1a);
            acc[mt][1][r] = fmaf(rad, w256b, b1b);
        }
    #pragma unroll
    for (int c = 0; c < 8; ++c) {
        short8 bf0 = *(const short8*)(We1bf + (c * 8 + w * 2 + 0) * 512 + lane * 8);
        short8 bf1 = *(const short8*)(We1bf + (c * 8 + w * 2 + 1) * 512 + lane * 8);
        #pragma unroll
        for (int mt = 0; mt < 4; ++mt) {
            short8 af = *(const short8*)(sA + ard + c * 2048 + mt * 128);
            acc[mt][0] = __builtin_amdgcn_mfma_f32_16x16x32_bf16(af, bf0, acc[mt][0], 0, 0, 0);
            acc[mt][1] = __builtin_amdgcn_mfma_f32_16x16x32_bf16(af, bf1, acc[mt][1], 0, 0, 0);
        }
    }
    #pragma unroll
    for (int mt = 0; mt < 4; ++mt)
        #pragma unroll
        for (int r = 0; r < 4; ++r)
            d[mt][r] = pkr(siluf(acc[mt][0][r]), siluf(acc[mt][1][r]));
    __syncthreads();   // barrier 2: all sA reads done -> aliases writable
    #pragma unroll
    for (int mt = 0; mt < 4; ++mt) {
        u16* bp = sT + (w * 4 + mt) * 512 + sbase;
        *(u32*)(bp + o0) = d[mt][0];
        *(u32*)(bp + o1) = d[mt][1];
        *(u32*)(bp + o2) = d[mt][2];
        *(u32*)(bp + o3) = d[mt][3];
    }
    __syncthreads();   // barrier 3: sT ready

    // ---- GEMM2: m = silu(t1 @ We2 + be2), K=128 ----
    #pragma unroll
    for (int mt = 0; mt < 4; ++mt)
        #pragma unroll
        for (int r = 0; r < 4; ++r) { acc[mt][0][r] = b2a; acc[mt][1][r] = b2b; }
    #pragma unroll
    for (int c = 0; c < 4; ++c) {
        short8 bf0 = *(const short8*)(We2bf + (c * 8 + w * 2 + 0) * 512 + lane * 8);
        short8 bf1 = *(const short8*)(We2bf + (c * 8 + w * 2 + 1) * 512 + lane * 8);
        #pragma unroll
        for (int mt = 0; mt < 4; ++mt) {
            short8 af = *(const short8*)(sT + (c * 4 + mt) * 512 + lsw);
            acc[mt][0] = __builtin_amdgcn_mfma_f32_16x16x32_bf16(af, bf0, acc[mt][0], 0, 0, 0);
            acc[mt][1] = __builtin_amdgcn_mfma_f32_16x16x32_bf16(af, bf1, acc[mt][1], 0, 0, 0);
        }
    }
    #pragma unroll
    for (int mt = 0; mt < 4; ++mt)
        #pragma unroll
        for (int r = 0; r < 4; ++r)
            d[mt][r] = pkr(siluf(acc[mt][0][r]), siluf(acc[mt][1][r]));
    // sM region (chunks 16..31) disjoint from sT reads -> no barrier before writes
    #pragma unroll
    for (int mt = 0; mt < 4; ++mt) {
        u16* bp = sM + (w * 4 + mt) * 512 + sbase;
        *(u32*)(bp + o0) = d[mt][0];
        *(u32*)(bp + o1) = d[mt][1];
        *(u32*)(bp + o2) = d[mt][2];
        *(u32*)(bp + o3) = d[mt][3];
    }
    #pragma unroll
    for (int mt = 0; mt < 4; ++mt)
        #pragma unroll
        for (int r = 0; r < 4; ++r) {
            int rw = sRow[mt * 16 + q * 4 + r];
            atomic_pk_add_bf16(aggbf + (size_t)rw * 128 + n0, d[mt][r]);
        }
    __syncthreads();   // barrier 4: sM ready

    // ---- GEMM3: u = silu(m @ Wc1 + bc1); coef fused via shfl reduce ----
    #pragma unroll
    for (int mt = 0; mt < 4; ++mt)
        #pragma unroll
        for (int r = 0; r < 4; ++r) { acc[mt][0][r] = b3a; acc[mt][1][r] = b3b; }
    #pragma unroll
    for (int c = 0; c < 4; ++c) {
        short8 bf0 = *(const short8*)(Wc1bf + (c * 8 + w * 2 + 0) * 512 + lane * 8);
        short8 bf1 = *(const short8*)(Wc1bf + (c * 8 + w * 2 + 1) * 512 + lane * 8);
        #pragma unroll
        for (int mt = 0; mt < 4; ++mt) {
            short8 af = *(const short8*)(sM + (c * 4 + mt) * 512 + lsw);
            acc[mt][0] = __builtin_amdgcn_mfma_f32_16x16x32_bf16(af, bf0, acc[mt][0], 0, 0, 0);
            acc[mt][1] = __builtin_amdgcn_mfma_f32_16x16x32_bf16(af, bf1, acc[mt][1], 0, 0, 0);
        }
    }
    #pragma unroll
    for (int mt = 0; mt < 4; ++mt)
        #pragma unroll
        for (int r = 0; r < 4; ++r) {
            float pv = fmaf(siluf(acc[mt][0][r]), wc2a, siluf(acc[mt][1][r]) * wc2b);
            pv += __shfl_xor(pv, 1);
            pv += __shfl_xor(pv, 2);
            pv += __shfl_xor(pv, 4);
            pv += __shfl_xor(pv, 8);
            if (m15 == 0) sCoefP[w][mt * 16 + q * 4 + r] = pv;
        }
    __syncthreads();   // barrier 5: coef partials ready

    // force scatter (64 edges x 3 axes)
    if (tid < 192) {
        int e = tid / 3, ax = tid - e * 3;
        float coef = sCoefP[0][e] + sCoefP[1][e] + sCoefP[2][e] + sCoefP[3][e];
        float tr = cdiff[(size_t)(e0 + e) * 3 + ax] * coef;
        tr = fminf(fmaxf(tr, -100.f), 100.f);
        atomicAdd(&fsum[(size_t)sRow[e] * 3 + ax], tr);
    }
}

// ---- node kernel: 64 nodes/block, 4 waves, ~34.5KB LDS (unchanged from R11) ----
__global__ __launch_bounds__(256, 4) void node_kernel(
    const u16* __restrict__ hbf,
    const float* __restrict__ bn1, const float* __restrict__ bn2,
    const float* __restrict__ bv1, const float* __restrict__ Wv2,
    const float* __restrict__ bv2,
    const u16* __restrict__ Wn1bf, const u16* __restrict__ Wn2bf,
    const u16* __restrict__ Wv1bf,
    const u16* __restrict__ aggbf, const float* __restrict__ fsum,
    const float* __restrict__ cnt, float* __restrict__ out)
{
    __shared__ u16 sX[16384];
    __shared__ float sBn1[128], sBn2[128], sBv1[128];
    __shared__ float sVelP[4][64];
    u16* sT = sX + 8192;

    const int tid = threadIdx.x;
    const int nblk = blockIdx.x * 64;
    const int w = tid >> 6;
    const int lane = tid & 63;
    const int m15 = lane & 15, q = lane >> 4;
    const int n0 = w * 32 + 2 * m15, n1 = n0 + 1;
    const int lsw = (lane ^ q) * 8;
    const int a_ = m15 >> 2;
    const int sbase = (a_ << 7) + (q << 5) + ((m15 & 3) << 1);
    const int o0 = (0 ^ a_) << 3, o1 = (1 ^ a_) << 3, o2 = (2 ^ a_) << 3, o3 = (3 ^ a_) << 3;
    const int ard = (m15 + 64 * q) * 8;

    if (tid < 192) {
        int r = tid / 3, ax = tid - r * 3;
        int n = nblk + r;
        if (n < NN)
            out[NN + (size_t)n * 3 + ax] = fsum[(size_t)n * 3 + ax] * __builtin_amdgcn_rcpf(fmaxf(cnt[n], 1.0f));
    }
    if (tid < 128) { sBn1[tid] = bn1[tid]; sBn2[tid] = bn2[tid]; sBv1[tid] = bv1[tid]; }
    const float wv2a = Wv2[n0], wv2b = Wv2[n1];

    {
        int r = tid & 63, j = tid >> 6;
        int n = nblk + r; if (n > NN - 1) n = NN - 1;
        const u16* src = ((j < 2) ? hbf : aggbf) + (size_t)n * 128 + (j & 1) * 64;
        #pragma unroll
        for (int i = 0; i < 8; ++i) {
            int slot = r + ((j * 8 + i) << 6);
            *(uint4*)&sX[slot * 8] = *(const uint4*)(src + i * 8);
        }
    }
    __syncthreads();

    f32x4 acc[4][2];

    {
        float b0 = sBn1[n0], b1 = sBn1[n1];
        #pragma unroll
        for (int mt = 0; mt < 4; ++mt)
            #pragma unroll
            for (int r = 0; r < 4; ++r) { acc[mt][0][r] = b0; acc[mt][1][r] = b1; }
    }
    #pragma unroll
    for (int c = 0; c < 8; ++c) {
        short8 bf0 = *(const short8*)(Wn1bf + (c * 8 + w * 2 + 0) * 512 + lane * 8);
        short8 bf1 = *(const short8*)(Wn1bf + (c * 8 + w * 2 + 1) * 512 + lane * 8);
        #pragma unroll
        for (int mt = 0; mt < 4; ++mt) {
            short8 af = *(const short8*)(sX + ard + c * 2048 + mt * 128);
            acc[mt][0] = __builtin_amdgcn_mfma_f32_16x16x32_bf16(af, bf0, acc[mt][0], 0, 0, 0);
            acc[mt][1] = __builtin_amdgcn_mfma_f32_16x16x32_bf16(af, bf1, acc[mt][1], 0, 0, 0);
        }
    }
    u32 dn[4][4];
    #pragma unroll
    for (int mt = 0; mt < 4; ++mt)
        #pragma unroll
        for (int r = 0; r < 4; ++r)
            dn[mt][r] = pkr(siluf(acc[mt][0][r]), siluf(acc[mt][1][r]));
    __syncthreads();
    #pragma unroll
    for (int mt = 0; mt < 4; ++mt) {
        u16* bp = sT + (w * 4 + mt) * 512 + sbase;
        *(u32*)(bp + o0) = dn[mt][0];
        *(u32*)(bp + o1) = dn[mt][1];
        *(u32*)(bp + o2) = dn[mt][2];
        *(u32*)(bp + o3) = dn[mt][3];
    }
    __syncthreads();

    {
        float b0 = sBn2[n0], b1 = sBn2[n1];
        #pragma unroll
        for (int mt = 0; mt < 4; ++mt)
            #pragma unroll
            for (int r = 0; r < 4; ++r) { acc[mt][0][r] = b0; acc[mt][1][r] = b1; }
    }
    #pragma unroll
    for (int c = 0; c < 4; ++c) {
        short8 bf0 = *(const short8*)(Wn2bf + (c * 8 + w * 2 + 0) * 512 + lane * 8);
        short8 bf1 = *(const short8*)(Wn2bf + (c * 8 + w * 2 + 1) * 512 + lane * 8);
        #pragma unroll
        for (int mt = 0; mt < 4; ++mt) {
            short8 af = *(const short8*)(sT + (c * 4 + mt) * 512 + lsw);
            acc[mt][0] = __builtin_amdgcn_mfma_f32_16x16x32_bf16(af, bf0, acc[mt][0], 0, 0, 0);
            acc[mt][1] = __builtin_amdgcn_mfma_f32_16x16x32_bf16(af, bf1, acc[mt][1], 0, 0, 0);
        }
    }
    #pragma unroll
    for (int mt = 0; mt < 4; ++mt)
        #pragma unroll
        for (int r = 0; r < 4; ++r) {
            int n = nblk + mt * 16 + q * 4 + r;
            if (n < NN) {
                f32x2 v; v.x = acc[mt][0][r]; v.y = acc[mt][1][r];
                *(f32x2*)(out + (size_t)4 * NN + (size_t)n * 128 + n0) = v;
            }
        }

    {
        float b0 = sBv1[n0], b1 = sBv1[n1];
        #pragma unroll
        for (int mt = 0; mt < 4; ++mt)
            #pragma unroll
            for (int r = 0; r < 4; ++r) { acc[mt][0][r] = b0; acc[mt][1][r] = b1; }
    }
    #pragma unroll
    for (int c = 0; c < 4; ++c) {
        short8 bf0 = *(const short8*)(Wv1bf + (c * 8 + w * 2 + 0) * 512 + lane * 8);
        short8 bf1 = *(const short8*)(Wv1bf + (c * 8 + w * 2 + 1) * 512 + lane * 8);
        #pragma unroll
        for (int mt = 0; mt < 4; ++mt) {
            short8 af = *(const short8*)(sX + ard + c * 2048 + mt * 128);
            acc[mt][0] = __builtin_amdgcn_mfma_f32_16x16x32_bf16(af, bf0, acc[mt][0], 0, 0, 0);
            acc[mt][1] = __builtin_amdgcn_mfma_f32_16x16x32_bf16(af, bf1, acc[mt][1], 0, 0, 0);
        }
    }
    #pragma unroll
    for (int mt = 0; mt < 4; ++mt)
        #pragma unroll
        for (int r = 0; r < 4; ++r) {
            float pv = fmaf(siluf(acc[mt][0][r]), wv2a, siluf(acc[mt][1][r]) * wv2b);
            pv += __shfl_xor(pv, 1);
            pv += __shfl_xor(pv, 2);
            pv += __shfl_xor(pv, 4);
            pv += __shfl_xor(pv, 8);
            if (m15 == 0) sVelP[w][mt * 16 + q * 4 + r] = pv;
        }
    __syncthreads();

    if (tid < 64) {
        int n = nblk + tid;
        if (n < NN)
            out[n] = bv2[0] + sVelP[0][tid] + sVelP[1][tid] + sVelP[2][tid] + sVelP[3][tid];
    }
}

extern "C" void kernel_launch(void* const* d_in, const int* in_sizes, int n_in,
                              void* d_out, int out_size, void* d_ws, size_t ws_size,
                              hipStream_t stream) {
    const float* h     = (const float*)d_in[0];
    const float* cdiff = (const float*)d_in[1];
    const int* row     = (const int*)d_in[2];
    const int* col     = (const int*)d_in[3];
    const float* We1 = (const float*)d_in[4];
    const float* be1 = (const float*)d_in[5];
    const float* We2 = (const float*)d_in[6];
    const float* be2 = (const float*)d_in[7];
    const float* Wn1 = (const float*)d_in[8];
    const float* bn1 = (const float*)d_in[9];
    const float* Wn2 = (const float*)d_in[10];
    const float* bn2 = (const float*)d_in[11];
    const float* Wc1 = (const float*)d_in[12];
    const float* bc1 = (const float*)d_in[13];
    const float* Wc2 = (const float*)d_in[14];
    const float* Wv1 = (const float*)d_in[15];
    const float* bv1 = (const float*)d_in[16];
    const float* Wv2 = (const float*)d_in[17];
    const float* bv2 = (const float*)d_in[18];

    u16* aggbf  = (u16*)d_ws;                           // [NN*128] bf16
    float* fsum = (float*)(aggbf + (size_t)NN * 128);   // [NN*3]
    float* cnt  = fsum + (size_t)NN * 3;                // [NN]
    u16* We1bf = (u16*)(cnt + NN);                      // [32768]
    u16* We2bf = We1bf + 32768;                         // [16384]
    u16* Wc1bf = We2bf + 16384;                         // [16384]
    u16* Wn1bf = Wc1bf + 16384;                         // [32768]
    u16* Wn2bf = Wn1bf + 32768;                         // [16384]
    u16* Wv1bf = Wn2bf + 16384;                         // [16384]
    u16* hbf   = Wv1bf + 16384;                         // [NN*128] bf16
    float* out = (float*)d_out;

    size_t zero_bytes = (size_t)NN * 128 * 2 + (size_t)NN * 3 * 4 + (size_t)NN * 4;
    hipMemsetAsync(d_ws, 0, zero_bytes, stream);

    hconv_kernel<<<3125, 256, 0, stream>>>(h, hbf);
    prep_kernel<<<512, 256, 0, stream>>>(We1, We2, Wc1, Wn1, Wn2, Wv1,
                                         We1bf, We2bf, Wc1bf, Wn1bf, Wn2bf, Wv1bf);
    edge_kernel<<<EE / 64, 256, 0, stream>>>(hbf, cdiff, row, col,
                                             We1, be1, be2, bc1, Wc2,
                                             We1bf, We2bf, Wc1bf,
                                             aggbf, fsum, cnt);
    node_kernel<<<(NN + 63) / 64, 256, 0, stream>>>(hbf, bn1, bn2, bv1, Wv2, bv2,
                                                    Wn1bf, Wn2bf, Wv1bf,
                                                    aggbf, fsum, cnt, out);
}